// Round 6
// baseline (86.901 us; speedup 1.0000x reference)
//
#include <hip/hip_runtime.h>
#include <cstdint>
#include <cstddef>

namespace {

constexpr int kB = 16;
constexpr int kH = 512;
constexpr int kW = 512;
constexpr int kHW = kH * kW;
constexpr int kNS = 37632;     // NUM_POINTS * OVERSAMPLE
constexpr int kNUNC = 9408;    // 0.75 * NUM_POINTS
constexpr int kNRAND = 3136;
constexpr int kNPTS = 12544;
constexpr int kBXB = 16;       // bbox partial blocks per batch
constexpr int kRPB = 4;        // rand-point blocks per batch
constexpr int kRGB2 = 16;      // region blocks per batch (1024 threads each)
constexpr int kSampleBlocks = (kB * kNS) / 512;   // 1176 (2 pts/thread)
constexpr int kBboxBlocks = kB * kBXB;            // 256
constexpr int kRandBlocks = kB * kRPB;            // 64
constexpr int kHStride = 1025;                    // hist row stride (words)

// workspace layout (bytes)
constexpr size_t OFF_PU  = 0;                                     // [B][NS] u32  |z| bits
constexpr size_t OFF_TRM = OFF_PU + (size_t)kB * kNS * 4;         // [B][NS] float4 (ce,p,t,pt)
constexpr size_t OFF_BBP = OFF_TRM + (size_t)kB * kNS * 16;       // [B][16][4] i32
constexpr size_t OFF_PLP = OFF_BBP + (size_t)kB * kBXB * 4 * 4;   // [B][4][4] f32 rand partials
constexpr size_t OFF_OSP = OFF_PLP + (size_t)kB * kRPB * 4 * 4;   // [B][4] f32 os sums
constexpr size_t OFF_RGP = OFF_OSP + (size_t)kB * 4 * 4;          // [B][16][5] f32 region partials

__device__ __forceinline__ int SW(int bin) {
  // row = bin&15, col = bin>>4; hist[k*1025+t] covers bins t*16+k.
  // 1025 % 32 == 1 -> adjacent bins land in distinct banks for the atomic phase;
  // row sums hist[k*kHStride + t] are lane-stride-1 (conflict-free).
  return (bin & 15) * kHStride + (bin >> 4);
}

} // namespace

__device__ __forceinline__ float sample_bilinear(const float* __restrict__ img,
                                                 float cx, float cy) {
  float x = cx * (float)kW - 0.5f;
  float y = cy * (float)kH - 0.5f;
  float x0f = floorf(x), y0f = floorf(y);
  float wx1 = x - x0f, wx0 = 1.0f - wx1;
  float wy1 = y - y0f, wy0 = 1.0f - wy1;
  int x0 = (int)x0f, y0 = (int)y0f;
  int x1 = x0 + 1, y1 = y0 + 1;
  int xc0 = min(max(x0, 0), kW - 1), xc1 = min(max(x1, 0), kW - 1);
  int yc0 = min(max(y0, 0), kH - 1), yc1 = min(max(y1, 0), kH - 1);
  float v00 = ((x0 >= 0) && (x0 < kW) && (y0 >= 0) && (y0 < kH)) ? img[yc0 * kW + xc0] : 0.0f;
  float v01 = ((x1 >= 0) && (x1 < kW) && (y0 >= 0) && (y0 < kH)) ? img[yc0 * kW + xc1] : 0.0f;
  float v10 = ((x0 >= 0) && (x0 < kW) && (y1 >= 0) && (y1 < kH)) ? img[yc1 * kW + xc0] : 0.0f;
  float v11 = ((x1 >= 0) && (x1 < kW) && (y1 >= 0) && (y1 < kH)) ? img[yc1 * kW + xc1] : 0.0f;
  return v00 * (wy0 * wx0) + v01 * (wy0 * wx1) + v10 * (wy1 * wx0) + v11 * (wy1 * wx1);
}

__device__ __forceinline__ void ce_pair(float z, float tt, float& ce, float& p) {
  float a = expf(-fabsf(z));
  ce = fmaxf(z, 0.0f) - z * tt + log1pf(a);
  float inv = 1.0f / (1.0f + a);
  p = (z >= 0.0f) ? inv : a * inv;
}

// ---- K1: os-point sampling+CE terms | bbox partials | rand-point CE partials ----
__global__ __launch_bounds__(256) void fused1_kernel(const float* __restrict__ pred,
                                                     const float* __restrict__ gt,
                                                     const float* __restrict__ coords_os,
                                                     const float* __restrict__ coords_rand,
                                                     unsigned* __restrict__ pu,
                                                     float4* __restrict__ trm,
                                                     int* __restrict__ bbp,
                                                     float* __restrict__ plp) {
  int blk = blockIdx.x;
  int t = threadIdx.x;

  if (blk < kSampleBlocks) {
    int pidx = blk * 256 + t;                // pair index; pairs never straddle batches
    float4 c2 = ((const float4*)coords_os)[pidx];
    int i0 = pidx * 2;
    int b = i0 / kNS;
    const float* pred_b = pred + (size_t)b * kHW;
    const float* gt_b = gt + (size_t)b * kHW;
    float z0 = sample_bilinear(pred_b, c2.x, c2.y);
    float z1 = sample_bilinear(pred_b, c2.z, c2.w);
    float t0 = sample_bilinear(gt_b, c2.x, c2.y);
    float t1 = sample_bilinear(gt_b, c2.z, c2.w);
    float ce0, p0, ce1, p1;
    ce_pair(z0, t0, ce0, p0);
    ce_pair(z1, t1, ce1, p1);
    unsigned u0 = __float_as_uint(z0) & 0x7fffffffu;
    unsigned u1 = __float_as_uint(z1) & 0x7fffffffu;
    *(uint2*)&pu[i0] = make_uint2(u0, u1);
    trm[i0] = make_float4(ce0, p0, t0, p0 * t0);
    trm[i0 + 1] = make_float4(ce1, p1, t1, p1 * t1);
    return;
  }

  if (blk < kSampleBlocks + kBboxBlocks) {
    __shared__ int r0[256], r1[256], r2[256], r3[256];
    int bb = blk - kSampleBlocks;
    int b = bb / kBXB;
    int c = bb % kBXB;
    constexpr int CHUNK4 = kHW / kBXB / 4;  // 4096 float4
    const float4* pred4 = (const float4*)(pred + (size_t)b * kHW) + (size_t)c * CHUNK4;
    int pbase = c * CHUNK4 * 4;
    int xmn = kW, xmx = -1, ymn = kH, ymx = -1;
    for (int i = t; i < CHUNK4; i += 256) {
      float4 z = pred4[i];
      int p = pbase + i * 4;
      int y = p >> 9;
      int x0 = p & (kW - 1);
      if (z.x > 0.0f) { xmn = min(xmn, x0);     xmx = max(xmx, x0);     ymn = min(ymn, y); ymx = max(ymx, y); }
      if (z.y > 0.0f) { xmn = min(xmn, x0 + 1); xmx = max(xmx, x0 + 1); ymn = min(ymn, y); ymx = max(ymx, y); }
      if (z.z > 0.0f) { xmn = min(xmn, x0 + 2); xmx = max(xmx, x0 + 2); ymn = min(ymn, y); ymx = max(ymx, y); }
      if (z.w > 0.0f) { xmn = min(xmn, x0 + 3); xmx = max(xmx, x0 + 3); ymn = min(ymn, y); ymx = max(ymx, y); }
    }
    r0[t] = xmn; r1[t] = xmx; r2[t] = ymn; r3[t] = ymx;
    __syncthreads();
    for (int s = 128; s > 0; s >>= 1) {
      if (t < s) {
        r0[t] = min(r0[t], r0[t + s]);
        r1[t] = max(r1[t], r1[t + s]);
        r2[t] = min(r2[t], r2[t + s]);
        r3[t] = max(r3[t], r3[t + s]);
      }
      __syncthreads();
    }
    if (t == 0) {
      int* o = bbp + ((size_t)b * kBXB + c) * 4;
      o[0] = r0[0]; o[1] = r1[0]; o[2] = r2[0]; o[3] = r3[0];
    }
    return;
  }

  // rand-point CE partials (independent of selection)
  {
    __shared__ float red[4][256];
    int q = blk - kSampleBlocks - kBboxBlocks;
    int b = q / kRPB;
    int c = q % kRPB;
    const float* pred_b = pred + (size_t)b * kHW;
    const float* gt_b = gt + (size_t)b * kHW;
    float ce_s = 0.0f, p_s = 0.0f, t_s = 0.0f, pt_s = 0.0f;
    for (int e = c * 256 + t; e < kNRAND; e += kRPB * 256) {
      float2 cc = *(const float2*)&coords_rand[((size_t)b * kNRAND + e) * 2];
      float z = sample_bilinear(pred_b, cc.x, cc.y);
      float tt = sample_bilinear(gt_b, cc.x, cc.y);
      float ce, p;
      ce_pair(z, tt, ce, p);
      ce_s += ce; p_s += p; t_s += tt; pt_s += p * tt;
    }
    red[0][t] = ce_s; red[1][t] = p_s; red[2][t] = t_s; red[3][t] = pt_s;
    __syncthreads();
    for (int s = 128; s > 0; s >>= 1) {
      if (t < s) {
        red[0][t] += red[0][t + s];
        red[1][t] += red[1][t + s];
        red[2][t] += red[2][t + s];
        red[3][t] += red[3][t + s];
      }
      __syncthreads();
    }
    if (t == 0) {
      float* o = plp + ((size_t)b * kRPB + c) * 4;
      o[0] = red[0][0]; o[1] = red[1][0]; o[2] = red[2][0]; o[3] = red[3][0];
    }
  }
}

// ---- K2: select+CE-sum (blocks 0..15) | region BCE+dice (blocks 16..271) ----
__global__ __launch_bounds__(1024) void fused2_kernel(const unsigned* __restrict__ pu,
                                                      const float4* __restrict__ trm,
                                                      const float* __restrict__ pred,
                                                      const float* __restrict__ gt,
                                                      const int* __restrict__ bbp,
                                                      float* __restrict__ osp,
                                                      float* __restrict__ rgp) {
  __shared__ unsigned smem[16 * kHStride + 1024];   // hist | sums/cand (69.7 KB)
  __shared__ int s_grp, s_cumbase, s_bstar, s_need, s_ccnt, s_round;
  int blk = blockIdx.x;
  int t = threadIdx.x;

  if (blk < kB) {
    constexpr int C = 37;            // ceil(37632/1024)
    constexpr int CAP = 1024;
    int b = blk;
    const unsigned* pu_b = pu + (size_t)b * kNS;
    const float4* trm_b = trm + (size_t)b * kNS;
    unsigned* hist = smem;
    unsigned* sums = smem + 16 * kHStride;

    for (int i = t; i < 16 * kHStride; i += 1024) hist[i] = 0u;
    if (t == 0) s_ccnt = 0;
    __syncthreads();

    // pass 1: histogram (coalesced u32 loads, swizzled bins)
    unsigned ub[C];
#pragma unroll
    for (int j = 0; j < C; ++j) {
      int idx = j * 1024 + t;
      if (idx < kNS) {
        unsigned u = pu_b[idx];
        ub[j] = u;
        atomicAdd(&hist[SW((int)(u >> 17))], 1u);
      } else {
        ub[j] = 0xffffffffu;
      }
    }
    __syncthreads();

    // boundary search: 16-bin sums -> 64-lane shfl scan -> 256-bin drill-down
    unsigned s = 0;
#pragma unroll
    for (int k = 0; k < 16; ++k) s += hist[k * kHStride + t];  // bins t*16..t*16+15
    sums[t] = s;
    __syncthreads();
    if (t < 64) {
      unsigned v = 0;
#pragma unroll
      for (int k = 0; k < 16; ++k) v += sums[t * 16 + k];      // bins t*256..t*256+255
      unsigned cum = v;
      for (int off = 1; off < 64; off <<= 1) {
        unsigned x = __shfl_up(cum, off, 64);
        if (t >= off) cum += x;
      }
      unsigned long long m = __ballot(cum >= (unsigned)kNUNC);
      int L = (int)(__ffsll((unsigned long long)m)) - 1;
      if (t == L) { s_grp = L; s_cumbase = (int)(cum - v); }
    }
    __syncthreads();
    if (t == 0) {
      unsigned cum = (unsigned)s_cumbase;
      int base = s_grp * 256;
      int bs = base + 255;
      unsigned nd = (unsigned)kNUNC - cum;
      for (int i = 0; i < 256; ++i) {
        unsigned h = hist[SW(base + i)];
        if (cum + h >= (unsigned)kNUNC) { bs = base + i; nd = (unsigned)kNUNC - cum; break; }
        cum += h;
      }
      s_bstar = bs;
      s_need = (int)nd;
    }
    __syncthreads();
    int bstar = s_bstar;
    int need = s_need;

    // pass 2: below-boundary -> accumulate terms; boundary bin -> candidates
    int* cand = (int*)sums;
    float ce_s = 0.0f, p_s = 0.0f, t_s = 0.0f, pt_s = 0.0f;
#pragma unroll
    for (int j = 0; j < C; ++j) {
      int idx = j * 1024 + t;
      if (idx < kNS) {
        int bin = (int)(ub[j] >> 17);
        if (bin < bstar) {
          float4 q = trm_b[idx];
          ce_s += q.x; p_s += q.y; t_s += q.z; pt_s += q.w;
        } else if (bin == bstar) {
          int pos = atomicAdd(&s_ccnt, 1);
          if (pos < CAP) cand[pos] = idx;
        }
      }
    }
    __syncthreads();
    int c = s_ccnt;

    if (c <= CAP) {
      for (int i = t; i < c; i += 1024) {
        int my = cand[i];
        int r = 0;
        for (int k = 0; k < c; ++k) r += (cand[k] < my) ? 1 : 0;
        if (r < need) {
          float4 q = trm_b[my];
          ce_s += q.x; p_s += q.y; t_s += q.z; pt_s += q.w;
        }
      }
      __syncthreads();
    } else {
      // deterministic ordered-scan fallback (duplicate-heavy pathological data)
      if (t == 0) s_round = 0;
      __syncthreads();
      for (int j = 0; j < C; ++j) {
        int idx = j * 1024 + t;
        unsigned flag = (idx < kNS && (int)(ub[j] >> 17) == bstar) ? 1u : 0u;
        sums[t] = flag;
        __syncthreads();
        for (int off = 1; off < 1024; off <<= 1) {
          unsigned v = (t >= off) ? sums[t - off] : 0u;
          __syncthreads();
          sums[t] += v;
          __syncthreads();
        }
        int base = s_round;
        if (flag && base + (int)(sums[t] - flag) < need) {
          float4 q = trm_b[idx];
          ce_s += q.x; p_s += q.y; t_s += q.z; pt_s += q.w;
        }
        __syncthreads();
        if (t == 0) s_round = base + (int)sums[1023];
        __syncthreads();
      }
    }

    // reduce 4 sums: per-wave shfl -> 16 wave partials -> thread 0
    float* redf = (float*)smem;   // hist region no longer needed
    float vals[4] = {ce_s, p_s, t_s, pt_s};
#pragma unroll
    for (int q = 0; q < 4; ++q) {
      float v = vals[q];
      for (int o = 32; o > 0; o >>= 1) v += __shfl_down(v, o, 64);
      if ((t & 63) == 0) redf[(t >> 6) * 4 + q] = v;
    }
    __syncthreads();
    if (t == 0) {
      float o0 = 0, o1 = 0, o2 = 0, o3 = 0;
      for (int w = 0; w < 16; ++w) {
        o0 += redf[w * 4 + 0]; o1 += redf[w * 4 + 1];
        o2 += redf[w * 4 + 2]; o3 += redf[w * 4 + 3];
      }
      float* o = osp + (size_t)b * 4;
      o[0] = o0; o[1] = o1; o[2] = o2; o[3] = o3;
    }
    return;
  }

  // region portion (1024 threads/block)
  {
    constexpr int CHUNK4 = kHW / kRGB2 / 4;  // 4096 float4 per block
    int q = blk - kB;
    int b = q / kRGB2;
    int c = q % kRGB2;
    const float4* pred4 = (const float4*)(pred + (size_t)b * kHW) + (size_t)c * CHUNK4;
    const float4* gt4 = (const float4*)(gt + (size_t)b * kHW) + (size_t)c * CHUNK4;

    int xmn = kW, xmx = -1, ymn = kH, ymx = -1;
#pragma unroll
    for (int u = 0; u < kBXB; ++u) {
      const int4 pb = *(const int4*)(bbp + ((size_t)b * kBXB + u) * 4);
      xmn = min(xmn, pb.x); xmx = max(xmx, pb.y);
      ymn = min(ymn, pb.z); ymx = max(ymx, pb.w);
    }
    bool empty = (xmx < 0);
    int x1 = empty ? 0 : xmn;
    int x2 = min(empty ? (kW - 1) : xmx, kW - 1);
    int y1 = empty ? 0 : ymn;
    int y2 = min(empty ? (kH - 1) : ymx, kH - 1);
    bool valid = (x2 > x1) && (y2 > y1);

    int pbase = c * CHUNK4 * 4;
    float wsum = 0.0f, bcew = 0.0f, inter = 0.0f, pw = 0.0f, gw = 0.0f;
    for (int i = t; i < CHUNK4; i += 1024) {
      float4 zv = pred4[i];
      float4 gv = gt4[i];
      int p = pbase + i * 4;
      int y = p >> 9;
      int x0 = p & (kW - 1);
      bool iny = valid && (y >= y1) && (y <= y2);
#pragma unroll
      for (int l = 0; l < 4; ++l) {
        float z = (l == 0) ? zv.x : (l == 1) ? zv.y : (l == 2) ? zv.z : zv.w;
        float g = (l == 0) ? gv.x : (l == 1) ? gv.y : (l == 2) ? gv.z : gv.w;
        int x = x0 + l;
        float w = (iny && x >= x1 && x <= x2) ? 2.0f : 0.5f;
        float a = expf(-fabsf(z));
        float sp = fmaxf(-z, 0.0f) + log1pf(a);   // softplus(-z) = -log_sigmoid(z)
        float bce = sp + (1.0f - g) * z;
        float inv = 1.0f / (1.0f + a);
        float pp = (z >= 0.0f) ? inv : a * inv;
        wsum += w;
        bcew += bce * w;
        inter += pp * g * w;
        pw += pp * w;
        gw += g * w;
      }
    }
    float* redf = (float*)smem;
    float vals[5] = {wsum, bcew, inter, pw, gw};
#pragma unroll
    for (int q5 = 0; q5 < 5; ++q5) {
      float v = vals[q5];
      for (int o = 32; o > 0; o >>= 1) v += __shfl_down(v, o, 64);
      if ((t & 63) == 0) redf[(t >> 6) * 5 + q5] = v;
    }
    __syncthreads();
    if (t == 0) {
      float o0 = 0, o1 = 0, o2 = 0, o3 = 0, o4 = 0;
      for (int w = 0; w < 16; ++w) {
        o0 += redf[w * 5 + 0]; o1 += redf[w * 5 + 1]; o2 += redf[w * 5 + 2];
        o3 += redf[w * 5 + 3]; o4 += redf[w * 5 + 4];
      }
      float* o = rgp + ((size_t)b * kRGB2 + c) * 5;
      o[0] = o0; o[1] = o1; o[2] = o2; o[3] = o3; o[4] = o4;
    }
  }
}

// ---- K3: finalize in f64 ----
__global__ __launch_bounds__(64) void finalize_kernel(const float* __restrict__ plp,
                                                      const float* __restrict__ osp,
                                                      const float* __restrict__ rgp,
                                                      float* __restrict__ out) {
  __shared__ double sh[kB][4];
  int t = threadIdx.x;
  if (t < kB) {
    const float* o = osp + (size_t)t * 4;
    double ce = o[0], p = o[1], tt = o[2], pt = o[3];
    for (int c = 0; c < kRPB; ++c) {
      const float* q = plp + ((size_t)t * kRPB + c) * 4;
      ce += q[0]; p += q[1]; tt += q[2]; pt += q[3];
    }
    double ws = 0, bc = 0, in = 0, pw = 0, gw = 0;
    for (int c = 0; c < kRGB2; ++c) {
      const float* q = rgp + ((size_t)t * kRGB2 + c) * 5;
      ws += q[0]; bc += q[1]; in += q[2]; pw += q[3]; gw += q[4];
    }
    sh[t][0] = ce / (double)kNPTS;
    sh[t][1] = 1.0 - (2.0 * pt + 1.0) / (p + tt + 1.0);
    double wss = ws > 1e-6 ? ws : 1e-6;
    sh[t][2] = bc / wss;
    sh[t][3] = 1.0 - (2.0 * in + 1.0) / (pw + gw + 1.0);
  }
  __syncthreads();
  if (t == 0) {
    double a = 0, b = 0, c = 0, d = 0;
    for (int i = 0; i < kB; ++i) { a += sh[i][0]; b += sh[i][1]; c += sh[i][2]; d += sh[i][3]; }
    out[0] = (float)(a / 16.0);
    out[1] = (float)(b / 16.0);
    out[2] = (float)(c / 16.0);
    out[3] = (float)(d / 16.0);
  }
}

extern "C" void kernel_launch(void* const* d_in, const int* in_sizes, int n_in,
                              void* d_out, int out_size, void* d_ws, size_t ws_size,
                              hipStream_t stream) {
  const float* pred = (const float*)d_in[0];
  const float* gt = (const float*)d_in[1];
  const float* coords_os = (const float*)d_in[2];
  const float* coords_rand = (const float*)d_in[3];
  float* out = (float*)d_out;
  char* ws = (char*)d_ws;

  unsigned* pu = (unsigned*)(ws + OFF_PU);
  float4* trm = (float4*)(ws + OFF_TRM);
  int* bbp = (int*)(ws + OFF_BBP);
  float* plp = (float*)(ws + OFF_PLP);
  float* osp = (float*)(ws + OFF_OSP);
  float* rgp = (float*)(ws + OFF_RGP);

  fused1_kernel<<<kSampleBlocks + kBboxBlocks + kRandBlocks, 256, 0, stream>>>(
      pred, gt, coords_os, coords_rand, pu, trm, bbp, plp);
  fused2_kernel<<<kB + kB * kRGB2, 1024, 0, stream>>>(pu, trm, pred, gt, bbp, osp, rgp);
  finalize_kernel<<<1, 64, 0, stream>>>(plp, osp, rgp, out);
}

// Round 7
// 76.816 us; speedup vs baseline: 1.1313x; 1.1313x over previous
//
#include <hip/hip_runtime.h>
#include <cstdint>
#include <cstddef>

namespace {

constexpr int kB = 16;
constexpr int kH = 512;
constexpr int kW = 512;
constexpr int kHW = kH * kW;
constexpr int kNS = 37632;     // NUM_POINTS * OVERSAMPLE
constexpr int kNUNC = 9408;    // 0.75 * NUM_POINTS
constexpr int kNRAND = 3136;
constexpr int kNPTS = 12544;
constexpr int kBXB = 16;       // bbox partial blocks per batch
constexpr int kRPB = 4;        // rand-point blocks per batch
constexpr int kRGB2 = 16;      // region blocks per batch (1024 threads each)
constexpr int kPairs = kNS / 2;                  // 18816 pairs per batch
constexpr int kSampSlots = 148;                  // slots per XCD (2 batches x 74 chunks)
constexpr int kSampleBlocks = 8 * kSampSlots;    // 1184
constexpr int kBboxBlocks = kB * kBXB;           // 256
constexpr int kRandBlocks = kB * kRPB;           // 64
constexpr int kHStride = 1025;                   // hist row stride (words)

// workspace layout (bytes)
constexpr size_t OFF_PU  = 0;                                     // [B][NS] u32  |z| bits
constexpr size_t OFF_TRM = OFF_PU + (size_t)kB * kNS * 4;         // [B][NS] float4 (ce,p,t,pt)
constexpr size_t OFF_BBP = OFF_TRM + (size_t)kB * kNS * 16;       // [B][16][4] i32
constexpr size_t OFF_PLP = OFF_BBP + (size_t)kB * kBXB * 4 * 4;   // [B][4][4] f32 rand partials
constexpr size_t OFF_OSP = OFF_PLP + (size_t)kB * kRPB * 4 * 4;   // [B][4] f32 os sums
constexpr size_t OFF_RGP = OFF_OSP + (size_t)kB * 4 * 4;          // [B][16][5] f32 region partials

// Swizzled hist: bin -> (bin&15)*1025 + (bin>>4). Row sums hist[k*1025+t] are
// lane-stride-1 (conflict-free); 1025%32==1 keeps adjacent bins in distinct banks.
__device__ __forceinline__ int SW(int bin) {
  return (bin & 15) * kHStride + (bin >> 4);
}

} // namespace

__device__ __forceinline__ float sample_bilinear(const float* __restrict__ img,
                                                 float cx, float cy) {
  float x = cx * (float)kW - 0.5f;
  float y = cy * (float)kH - 0.5f;
  float x0f = floorf(x), y0f = floorf(y);
  float wx1 = x - x0f, wx0 = 1.0f - wx1;
  float wy1 = y - y0f, wy0 = 1.0f - wy1;
  int x0 = (int)x0f, y0 = (int)y0f;
  int x1 = x0 + 1, y1 = y0 + 1;
  int xc0 = min(max(x0, 0), kW - 1), xc1 = min(max(x1, 0), kW - 1);
  int yc0 = min(max(y0, 0), kH - 1), yc1 = min(max(y1, 0), kH - 1);
  float v00 = ((x0 >= 0) && (x0 < kW) && (y0 >= 0) && (y0 < kH)) ? img[yc0 * kW + xc0] : 0.0f;
  float v01 = ((x1 >= 0) && (x1 < kW) && (y0 >= 0) && (y0 < kH)) ? img[yc0 * kW + xc1] : 0.0f;
  float v10 = ((x0 >= 0) && (x0 < kW) && (y1 >= 0) && (y1 < kH)) ? img[yc1 * kW + xc0] : 0.0f;
  float v11 = ((x1 >= 0) && (x1 < kW) && (y1 >= 0) && (y1 < kH)) ? img[yc1 * kW + xc1] : 0.0f;
  return v00 * (wy0 * wx0) + v01 * (wy0 * wx1) + v10 * (wy1 * wx0) + v11 * (wy1 * wx1);
}

__device__ __forceinline__ void ce_pair(float z, float tt, float& ce, float& p) {
  float a = expf(-fabsf(z));
  ce = fmaxf(z, 0.0f) - z * tt + log1pf(a);
  float inv = 1.0f / (1.0f + a);
  p = (z >= 0.0f) ? inv : a * inv;
}

// ---- K1: os sampling+CE | bbox partials | rand CE partials; XCD-clustered ----
// XCD x (= blockIdx%8) handles only batches 2x, 2x+1 in every sub-phase, so each
// XCD's L2 working set is pred+gt for 2 batches = 4 MB (one L2's capacity).
__global__ __launch_bounds__(256) void fused1_kernel(const float* __restrict__ pred,
                                                     const float* __restrict__ gt,
                                                     const float* __restrict__ coords_os,
                                                     const float* __restrict__ coords_rand,
                                                     unsigned* __restrict__ pu,
                                                     float4* __restrict__ trm,
                                                     int* __restrict__ bbp,
                                                     float* __restrict__ plp) {
  int blk = blockIdx.x;
  int t = threadIdx.x;

  if (blk < kSampleBlocks) {
    int x = blk & 7;
    int s = blk >> 3;                 // 0..147
    int b = x * 2 + (s & 1);
    int chunk = s >> 1;               // 0..73
    int pib = chunk * 256 + t;        // pair index within batch
    if (pib >= kPairs) return;
    size_t gp = (size_t)b * kPairs + pib;   // global pair index
    float4 c2 = ((const float4*)coords_os)[gp];
    size_t i0 = gp * 2;
    const float* pred_b = pred + (size_t)b * kHW;
    const float* gt_b = gt + (size_t)b * kHW;
    float z0 = sample_bilinear(pred_b, c2.x, c2.y);
    float z1 = sample_bilinear(pred_b, c2.z, c2.w);
    float t0 = sample_bilinear(gt_b, c2.x, c2.y);
    float t1 = sample_bilinear(gt_b, c2.z, c2.w);
    float ce0, p0, ce1, p1;
    ce_pair(z0, t0, ce0, p0);
    ce_pair(z1, t1, ce1, p1);
    unsigned u0 = __float_as_uint(z0) & 0x7fffffffu;
    unsigned u1 = __float_as_uint(z1) & 0x7fffffffu;
    *(uint2*)&pu[i0] = make_uint2(u0, u1);
    trm[i0] = make_float4(ce0, p0, t0, p0 * t0);
    trm[i0 + 1] = make_float4(ce1, p1, t1, p1 * t1);
    return;
  }

  if (blk < kSampleBlocks + kBboxBlocks) {
    __shared__ int r0[256], r1[256], r2[256], r3[256];
    int i = blk - kSampleBlocks;      // 1184%8==0 -> xcd = i%8
    int x = i & 7;
    int s = i >> 3;                   // 0..31
    int b = x * 2 + (s & 1);
    int c = s >> 1;                   // 0..15
    constexpr int CHUNK4 = kHW / kBXB / 4;  // 4096 float4
    const float4* pred4 = (const float4*)(pred + (size_t)b * kHW) + (size_t)c * CHUNK4;
    int pbase = c * CHUNK4 * 4;
    int xmn = kW, xmx = -1, ymn = kH, ymx = -1;
    for (int i4 = t; i4 < CHUNK4; i4 += 256) {
      float4 z = pred4[i4];
      int p = pbase + i4 * 4;
      int y = p >> 9;
      int x0 = p & (kW - 1);
      if (z.x > 0.0f) { xmn = min(xmn, x0);     xmx = max(xmx, x0);     ymn = min(ymn, y); ymx = max(ymx, y); }
      if (z.y > 0.0f) { xmn = min(xmn, x0 + 1); xmx = max(xmx, x0 + 1); ymn = min(ymn, y); ymx = max(ymx, y); }
      if (z.z > 0.0f) { xmn = min(xmn, x0 + 2); xmx = max(xmx, x0 + 2); ymn = min(ymn, y); ymx = max(ymx, y); }
      if (z.w > 0.0f) { xmn = min(xmn, x0 + 3); xmx = max(xmx, x0 + 3); ymn = min(ymn, y); ymx = max(ymx, y); }
    }
    r0[t] = xmn; r1[t] = xmx; r2[t] = ymn; r3[t] = ymx;
    __syncthreads();
    for (int s2 = 128; s2 > 0; s2 >>= 1) {
      if (t < s2) {
        r0[t] = min(r0[t], r0[t + s2]);
        r1[t] = max(r1[t], r1[t + s2]);
        r2[t] = min(r2[t], r2[t + s2]);
        r3[t] = max(r3[t], r3[t + s2]);
      }
      __syncthreads();
    }
    if (t == 0) {
      int* o = bbp + ((size_t)b * kBXB + c) * 4;
      o[0] = r0[0]; o[1] = r1[0]; o[2] = r2[0]; o[3] = r3[0];
    }
    return;
  }

  // rand-point CE partials
  {
    __shared__ float red[4][256];
    int i = blk - kSampleBlocks - kBboxBlocks;   // 1440%8==0 -> xcd = i%8
    int x = i & 7;
    int s = i >> 3;                   // 0..7
    int b = x * 2 + (s & 1);
    int c = s >> 1;                   // 0..3
    const float* pred_b = pred + (size_t)b * kHW;
    const float* gt_b = gt + (size_t)b * kHW;
    float ce_s = 0.0f, p_s = 0.0f, t_s = 0.0f, pt_s = 0.0f;
    for (int e = c * 256 + t; e < kNRAND; e += kRPB * 256) {
      float2 cc = *(const float2*)&coords_rand[((size_t)b * kNRAND + e) * 2];
      float z = sample_bilinear(pred_b, cc.x, cc.y);
      float tt = sample_bilinear(gt_b, cc.x, cc.y);
      float ce, p;
      ce_pair(z, tt, ce, p);
      ce_s += ce; p_s += p; t_s += tt; pt_s += p * tt;
    }
    red[0][t] = ce_s; red[1][t] = p_s; red[2][t] = t_s; red[3][t] = pt_s;
    __syncthreads();
    for (int s2 = 128; s2 > 0; s2 >>= 1) {
      if (t < s2) {
        red[0][t] += red[0][t + s2];
        red[1][t] += red[1][t + s2];
        red[2][t] += red[2][t + s2];
        red[3][t] += red[3][t + s2];
      }
      __syncthreads();
    }
    if (t == 0) {
      float* o = plp + ((size_t)b * kRPB + c) * 4;
      o[0] = red[0][0]; o[1] = red[1][0]; o[2] = red[2][0]; o[3] = red[3][0];
    }
  }
}

// ---- K2: select+CE-sum (blocks 0..15) | region (blocks 16..271); XCD-clustered ----
__global__ __launch_bounds__(1024) void fused2_kernel(const unsigned* __restrict__ pu,
                                                      const float4* __restrict__ trm,
                                                      const float* __restrict__ pred,
                                                      const float* __restrict__ gt,
                                                      const int* __restrict__ bbp,
                                                      float* __restrict__ osp,
                                                      float* __restrict__ rgp) {
  __shared__ unsigned smem[16 * kHStride + 1024];   // hist | sums/cand (69.7 KB)
  __shared__ int s_bstar, s_need, s_ccnt, s_round;
  int blk = blockIdx.x;
  int t = threadIdx.x;

  if (blk < kB) {
    constexpr int C = 37;            // ceil(37632/1024)
    constexpr int CAP = 1024;
    int b = (blk & 7) * 2 + (blk >> 3);   // batch b on XCD b/2 (matches K1 residue)
    const unsigned* pu_b = pu + (size_t)b * kNS;
    const float4* trm_b = trm + (size_t)b * kNS;
    unsigned* hist = smem;
    unsigned* sums = smem + 16 * kHStride;

    for (int i = t; i < 16 * kHStride; i += 1024) hist[i] = 0u;
    if (t == 0) s_ccnt = 0;
    __syncthreads();

    // pass 1: histogram (coalesced u32 loads, swizzled bins)
    unsigned ub[C];
#pragma unroll
    for (int j = 0; j < C; ++j) {
      int idx = j * 1024 + t;
      if (idx < kNS) {
        unsigned u = pu_b[idx];
        ub[j] = u;
        atomicAdd(&hist[SW((int)(u >> 17))], 1u);
      } else {
        ub[j] = 0xffffffffu;
      }
    }
    __syncthreads();

    // boundary search, fully wave-parallel:
    // 16384 bins -> sums[1024] (16 bins each) -> 64 supergroups (256 bins each)
    unsigned s = 0;
#pragma unroll
    for (int k = 0; k < 16; ++k) s += hist[k * kHStride + t];  // bins t*16..t*16+15
    sums[t] = s;
    __syncthreads();
    if (t < 64) {
      const unsigned K = (unsigned)kNUNC;
      unsigned v = 0;
#pragma unroll
      for (int k = 0; k < 16; ++k) v += sums[t * 16 + k];      // bins t*256..
      unsigned cum = v;
      for (int off = 1; off < 64; off <<= 1) {
        unsigned xx = __shfl_up(cum, off, 64);
        if (t >= off) cum += xx;
      }
      unsigned long long m = __ballot(cum >= K);
      int L = (int)__ffsll(m) - 1;
      unsigned base1 = __shfl(cum - v, L, 64);                 // prefix before group L
      // phase 2: 16 sums entries inside group L
      unsigned v2 = (t < 16) ? sums[L * 16 + t] : 0u;
      unsigned cum2 = v2;
      for (int off = 1; off < 16; off <<= 1) {
        unsigned xx = __shfl_up(cum2, off, 64);
        if (t >= off) cum2 += xx;
      }
      unsigned long long m2 = __ballot((t < 16) && (base1 + cum2 >= K));
      int M = (int)__ffsll(m2) - 1;
      unsigned base2 = __shfl(base1 + cum2 - v2, M, 64);       // prefix before entry E
      int E = L * 16 + M;
      // phase 3: 16 bins inside entry E; bin E*16+t lives at hist[t*kHStride + E]
      unsigned v3 = (t < 16) ? hist[t * kHStride + E] : 0u;
      unsigned cum3 = v3;
      for (int off = 1; off < 16; off <<= 1) {
        unsigned xx = __shfl_up(cum3, off, 64);
        if (t >= off) cum3 += xx;
      }
      unsigned long long m3 = __ballot((t < 16) && (base2 + cum3 >= K));
      int F = (int)__ffsll(m3) - 1;
      if (t == F) {
        s_bstar = E * 16 + F;
        s_need = (int)(K - (base2 + cum3 - v3));
      }
    }
    __syncthreads();
    int bstar = s_bstar;
    int need = s_need;

    // pass 2: below-boundary -> accumulate terms; boundary bin -> candidates
    int* cand = (int*)sums;
    float ce_s = 0.0f, p_s = 0.0f, t_s = 0.0f, pt_s = 0.0f;
#pragma unroll
    for (int j = 0; j < C; ++j) {
      int idx = j * 1024 + t;
      if (idx < kNS) {
        int bin = (int)(ub[j] >> 17);
        if (bin < bstar) {
          float4 q = trm_b[idx];
          ce_s += q.x; p_s += q.y; t_s += q.z; pt_s += q.w;
        } else if (bin == bstar) {
          int pos = atomicAdd(&s_ccnt, 1);
          if (pos < CAP) cand[pos] = idx;
        }
      }
    }
    __syncthreads();
    int c = s_ccnt;

    if (c <= CAP) {
      for (int i = t; i < c; i += 1024) {
        int my = cand[i];
        int r = 0;
        for (int k = 0; k < c; ++k) r += (cand[k] < my) ? 1 : 0;
        if (r < need) {
          float4 q = trm_b[my];
          ce_s += q.x; p_s += q.y; t_s += q.z; pt_s += q.w;
        }
      }
      __syncthreads();
    } else {
      // deterministic ordered-scan fallback (duplicate-heavy pathological data)
      if (t == 0) s_round = 0;
      __syncthreads();
      for (int j = 0; j < C; ++j) {
        int idx = j * 1024 + t;
        unsigned flag = (idx < kNS && (int)(ub[j] >> 17) == bstar) ? 1u : 0u;
        sums[t] = flag;
        __syncthreads();
        for (int off = 1; off < 1024; off <<= 1) {
          unsigned v = (t >= off) ? sums[t - off] : 0u;
          __syncthreads();
          sums[t] += v;
          __syncthreads();
        }
        int base = s_round;
        if (flag && base + (int)(sums[t] - flag) < need) {
          float4 q = trm_b[idx];
          ce_s += q.x; p_s += q.y; t_s += q.z; pt_s += q.w;
        }
        __syncthreads();
        if (t == 0) s_round = base + (int)sums[1023];
        __syncthreads();
      }
    }

    // reduce 4 sums: per-wave shfl -> 16 wave partials -> thread 0
    float* redf = (float*)smem;
    float vals[4] = {ce_s, p_s, t_s, pt_s};
#pragma unroll
    for (int q = 0; q < 4; ++q) {
      float v = vals[q];
      for (int o = 32; o > 0; o >>= 1) v += __shfl_down(v, o, 64);
      if ((t & 63) == 0) redf[(t >> 6) * 4 + q] = v;
    }
    __syncthreads();
    if (t == 0) {
      float o0 = 0, o1 = 0, o2 = 0, o3 = 0;
      for (int w = 0; w < 16; ++w) {
        o0 += redf[w * 4 + 0]; o1 += redf[w * 4 + 1];
        o2 += redf[w * 4 + 2]; o3 += redf[w * 4 + 3];
      }
      float* o = osp + (size_t)b * 4;
      o[0] = o0; o[1] = o1; o[2] = o2; o[3] = o3;
    }
    return;
  }

  // region portion (1024 threads/block), XCD-clustered: batch b on XCD b/2
  {
    constexpr int CHUNK4 = kHW / kRGB2 / 4;  // 4096 float4 per block
    int i = blk - kB;                 // 16%8==0 -> xcd = i%8
    int x = i & 7;
    int s = i >> 3;                   // 0..31
    int b = x * 2 + (s & 1);
    int c = s >> 1;                   // 0..15
    const float4* pred4 = (const float4*)(pred + (size_t)b * kHW) + (size_t)c * CHUNK4;
    const float4* gt4 = (const float4*)(gt + (size_t)b * kHW) + (size_t)c * CHUNK4;

    int xmn = kW, xmx = -1, ymn = kH, ymx = -1;
#pragma unroll
    for (int u = 0; u < kBXB; ++u) {
      const int4 pb = *(const int4*)(bbp + ((size_t)b * kBXB + u) * 4);
      xmn = min(xmn, pb.x); xmx = max(xmx, pb.y);
      ymn = min(ymn, pb.z); ymx = max(ymx, pb.w);
    }
    bool empty = (xmx < 0);
    int x1 = empty ? 0 : xmn;
    int x2 = min(empty ? (kW - 1) : xmx, kW - 1);
    int y1 = empty ? 0 : ymn;
    int y2 = min(empty ? (kH - 1) : ymx, kH - 1);
    bool valid = (x2 > x1) && (y2 > y1);

    int pbase = c * CHUNK4 * 4;
    float wsum = 0.0f, bcew = 0.0f, inter = 0.0f, pw = 0.0f, gw = 0.0f;
    for (int i4 = t; i4 < CHUNK4; i4 += 1024) {
      float4 zv = pred4[i4];
      float4 gv = gt4[i4];
      int p = pbase + i4 * 4;
      int y = p >> 9;
      int x0 = p & (kW - 1);
      bool iny = valid && (y >= y1) && (y <= y2);
#pragma unroll
      for (int l = 0; l < 4; ++l) {
        float z = (l == 0) ? zv.x : (l == 1) ? zv.y : (l == 2) ? zv.z : zv.w;
        float g = (l == 0) ? gv.x : (l == 1) ? gv.y : (l == 2) ? gv.z : gv.w;
        int xx = x0 + l;
        float w = (iny && xx >= x1 && xx <= x2) ? 2.0f : 0.5f;
        float a = expf(-fabsf(z));
        float sp = fmaxf(-z, 0.0f) + log1pf(a);   // softplus(-z) = -log_sigmoid(z)
        float bce = sp + (1.0f - g) * z;
        float inv = 1.0f / (1.0f + a);
        float pp = (z >= 0.0f) ? inv : a * inv;
        wsum += w;
        bcew += bce * w;
        inter += pp * g * w;
        pw += pp * w;
        gw += g * w;
      }
    }
    float* redf = (float*)smem;
    float vals[5] = {wsum, bcew, inter, pw, gw};
#pragma unroll
    for (int q5 = 0; q5 < 5; ++q5) {
      float v = vals[q5];
      for (int o = 32; o > 0; o >>= 1) v += __shfl_down(v, o, 64);
      if ((t & 63) == 0) redf[(t >> 6) * 5 + q5] = v;
    }
    __syncthreads();
    if (t == 0) {
      float o0 = 0, o1 = 0, o2 = 0, o3 = 0, o4 = 0;
      for (int w = 0; w < 16; ++w) {
        o0 += redf[w * 5 + 0]; o1 += redf[w * 5 + 1]; o2 += redf[w * 5 + 2];
        o3 += redf[w * 5 + 3]; o4 += redf[w * 5 + 4];
      }
      float* o = rgp + ((size_t)b * kRGB2 + c) * 5;
      o[0] = o0; o[1] = o1; o[2] = o2; o[3] = o3; o[4] = o4;
    }
  }
}

// ---- K3: finalize in f64 ----
__global__ __launch_bounds__(64) void finalize_kernel(const float* __restrict__ plp,
                                                      const float* __restrict__ osp,
                                                      const float* __restrict__ rgp,
                                                      float* __restrict__ out) {
  __shared__ double sh[kB][4];
  int t = threadIdx.x;
  if (t < kB) {
    const float* o = osp + (size_t)t * 4;
    double ce = o[0], p = o[1], tt = o[2], pt = o[3];
    for (int c = 0; c < kRPB; ++c) {
      const float* q = plp + ((size_t)t * kRPB + c) * 4;
      ce += q[0]; p += q[1]; tt += q[2]; pt += q[3];
    }
    double ws = 0, bc = 0, in = 0, pw = 0, gw = 0;
    for (int c = 0; c < kRGB2; ++c) {
      const float* q = rgp + ((size_t)t * kRGB2 + c) * 5;
      ws += q[0]; bc += q[1]; in += q[2]; pw += q[3]; gw += q[4];
    }
    sh[t][0] = ce / (double)kNPTS;
    sh[t][1] = 1.0 - (2.0 * pt + 1.0) / (p + tt + 1.0);
    double wss = ws > 1e-6 ? ws : 1e-6;
    sh[t][2] = bc / wss;
    sh[t][3] = 1.0 - (2.0 * in + 1.0) / (pw + gw + 1.0);
  }
  __syncthreads();
  if (t == 0) {
    double a = 0, b = 0, c = 0, d = 0;
    for (int i = 0; i < kB; ++i) { a += sh[i][0]; b += sh[i][1]; c += sh[i][2]; d += sh[i][3]; }
    out[0] = (float)(a / 16.0);
    out[1] = (float)(b / 16.0);
    out[2] = (float)(c / 16.0);
    out[3] = (float)(d / 16.0);
  }
}

extern "C" void kernel_launch(void* const* d_in, const int* in_sizes, int n_in,
                              void* d_out, int out_size, void* d_ws, size_t ws_size,
                              hipStream_t stream) {
  const float* pred = (const float*)d_in[0];
  const float* gt = (const float*)d_in[1];
  const float* coords_os = (const float*)d_in[2];
  const float* coords_rand = (const float*)d_in[3];
  float* out = (float*)d_out;
  char* ws = (char*)d_ws;

  unsigned* pu = (unsigned*)(ws + OFF_PU);
  float4* trm = (float4*)(ws + OFF_TRM);
  int* bbp = (int*)(ws + OFF_BBP);
  float* plp = (float*)(ws + OFF_PLP);
  float* osp = (float*)(ws + OFF_OSP);
  float* rgp = (float*)(ws + OFF_RGP);

  fused1_kernel<<<kSampleBlocks + kBboxBlocks + kRandBlocks, 256, 0, stream>>>(
      pred, gt, coords_os, coords_rand, pu, trm, bbp, plp);
  fused2_kernel<<<kB + kB * kRGB2, 1024, 0, stream>>>(pu, trm, pred, gt, bbp, osp, rgp);
  finalize_kernel<<<1, 64, 0, stream>>>(plp, osp, rgp, out);
}

// Round 8
// 74.613 us; speedup vs baseline: 1.1647x; 1.0295x over previous
//
#include <hip/hip_runtime.h>
#include <cstdint>
#include <cstddef>

namespace {

constexpr int kB = 16;
constexpr int kH = 512;
constexpr int kW = 512;
constexpr int kHW = kH * kW;
constexpr int kNS = 37632;     // NUM_POINTS * OVERSAMPLE
constexpr int kNS4 = kNS / 4;  // 9408 uint4/float4 groups per batch
constexpr int kNUNC = 9408;    // 0.75 * NUM_POINTS
constexpr int kNRAND = 3136;
constexpr int kNPTS = 12544;
constexpr int kBXB = 16;       // bbox partial blocks per batch
constexpr int kRPB = 4;        // rand-point blocks per batch
constexpr int kRGB2 = 16;      // region blocks per batch (1024 threads each)
constexpr int kPairs = kNS / 2;                  // 18816 pairs per batch
constexpr int kSampSlots = 148;                  // slots per XCD (2 batches x 74 chunks)
constexpr int kSampleBlocks = 8 * kSampSlots;    // 1184
constexpr int kBboxBlocks = kB * kBXB;           // 256
constexpr int kRandBlocks = kB * kRPB;           // 64
constexpr int kHStride = 1025;                   // hist row stride (words)

// workspace layout (bytes)
constexpr size_t OFF_PU  = 0;                                     // [B][NS] u32  |z| bits
constexpr size_t OFF_TRM = OFF_PU + (size_t)kB * kNS * 4;         // [B][NS] float4 (ce,p,t,pt)
constexpr size_t OFF_BBP = OFF_TRM + (size_t)kB * kNS * 16;       // [B][16][4] i32
constexpr size_t OFF_PLP = OFF_BBP + (size_t)kB * kBXB * 4 * 4;   // [B][4][4] f32 rand partials
constexpr size_t OFF_OSP = OFF_PLP + (size_t)kB * kRPB * 4 * 4;   // [B][4] f32 os sums
constexpr size_t OFF_RGP = OFF_OSP + (size_t)kB * 4 * 4;          // [B][16][5] f32 region partials

// Swizzled hist: bin -> (bin&15)*1025 + (bin>>4). Row sums hist[k*1025+t] are
// lane-stride-1 (conflict-free); 1025%32==1 keeps adjacent bins in distinct banks.
__device__ __forceinline__ int SW(int bin) {
  return (bin & 15) * kHStride + (bin >> 4);
}

} // namespace

__device__ __forceinline__ float sample_bilinear(const float* __restrict__ img,
                                                 float cx, float cy) {
  float x = cx * (float)kW - 0.5f;
  float y = cy * (float)kH - 0.5f;
  float x0f = floorf(x), y0f = floorf(y);
  float wx1 = x - x0f, wx0 = 1.0f - wx1;
  float wy1 = y - y0f, wy0 = 1.0f - wy1;
  int x0 = (int)x0f, y0 = (int)y0f;
  int x1 = x0 + 1, y1 = y0 + 1;
  int xc0 = min(max(x0, 0), kW - 1), xc1 = min(max(x1, 0), kW - 1);
  int yc0 = min(max(y0, 0), kH - 1), yc1 = min(max(y1, 0), kH - 1);
  float v00 = ((x0 >= 0) && (x0 < kW) && (y0 >= 0) && (y0 < kH)) ? img[yc0 * kW + xc0] : 0.0f;
  float v01 = ((x1 >= 0) && (x1 < kW) && (y0 >= 0) && (y0 < kH)) ? img[yc0 * kW + xc1] : 0.0f;
  float v10 = ((x0 >= 0) && (x0 < kW) && (y1 >= 0) && (y1 < kH)) ? img[yc1 * kW + xc0] : 0.0f;
  float v11 = ((x1 >= 0) && (x1 < kW) && (y1 >= 0) && (y1 < kH)) ? img[yc1 * kW + xc1] : 0.0f;
  return v00 * (wy0 * wx0) + v01 * (wy0 * wx1) + v10 * (wy1 * wx0) + v11 * (wy1 * wx1);
}

__device__ __forceinline__ void ce_pair(float z, float tt, float& ce, float& p) {
  float a = expf(-fabsf(z));
  ce = fmaxf(z, 0.0f) - z * tt + log1pf(a);
  float inv = 1.0f / (1.0f + a);
  p = (z >= 0.0f) ? inv : a * inv;
}

// ---- K1: os sampling+CE | bbox partials | rand CE partials; XCD-clustered ----
__global__ __launch_bounds__(256) void fused1_kernel(const float* __restrict__ pred,
                                                     const float* __restrict__ gt,
                                                     const float* __restrict__ coords_os,
                                                     const float* __restrict__ coords_rand,
                                                     unsigned* __restrict__ pu,
                                                     float4* __restrict__ trm,
                                                     int* __restrict__ bbp,
                                                     float* __restrict__ plp) {
  int blk = blockIdx.x;
  int t = threadIdx.x;

  if (blk < kSampleBlocks) {
    int x = blk & 7;
    int s = blk >> 3;                 // 0..147
    int b = x * 2 + (s & 1);
    int chunk = s >> 1;               // 0..73
    int pib = chunk * 256 + t;        // pair index within batch
    if (pib >= kPairs) return;
    size_t gp = (size_t)b * kPairs + pib;   // global pair index
    float4 c2 = ((const float4*)coords_os)[gp];
    size_t i0 = gp * 2;
    const float* pred_b = pred + (size_t)b * kHW;
    const float* gt_b = gt + (size_t)b * kHW;
    float z0 = sample_bilinear(pred_b, c2.x, c2.y);
    float z1 = sample_bilinear(pred_b, c2.z, c2.w);
    float t0 = sample_bilinear(gt_b, c2.x, c2.y);
    float t1 = sample_bilinear(gt_b, c2.z, c2.w);
    float ce0, p0, ce1, p1;
    ce_pair(z0, t0, ce0, p0);
    ce_pair(z1, t1, ce1, p1);
    unsigned u0 = __float_as_uint(z0) & 0x7fffffffu;
    unsigned u1 = __float_as_uint(z1) & 0x7fffffffu;
    *(uint2*)&pu[i0] = make_uint2(u0, u1);
    trm[i0] = make_float4(ce0, p0, t0, p0 * t0);
    trm[i0 + 1] = make_float4(ce1, p1, t1, p1 * t1);
    return;
  }

  if (blk < kSampleBlocks + kBboxBlocks) {
    __shared__ int r0[256], r1[256], r2[256], r3[256];
    int i = blk - kSampleBlocks;
    int x = i & 7;
    int s = i >> 3;                   // 0..31
    int b = x * 2 + (s & 1);
    int c = s >> 1;                   // 0..15
    constexpr int CHUNK4 = kHW / kBXB / 4;  // 4096 float4
    const float4* pred4 = (const float4*)(pred + (size_t)b * kHW) + (size_t)c * CHUNK4;
    int pbase = c * CHUNK4 * 4;
    int xmn = kW, xmx = -1, ymn = kH, ymx = -1;
    for (int i4 = t; i4 < CHUNK4; i4 += 256) {
      float4 z = pred4[i4];
      int p = pbase + i4 * 4;
      int y = p >> 9;
      int x0 = p & (kW - 1);
      if (z.x > 0.0f) { xmn = min(xmn, x0);     xmx = max(xmx, x0);     ymn = min(ymn, y); ymx = max(ymx, y); }
      if (z.y > 0.0f) { xmn = min(xmn, x0 + 1); xmx = max(xmx, x0 + 1); ymn = min(ymn, y); ymx = max(ymx, y); }
      if (z.z > 0.0f) { xmn = min(xmn, x0 + 2); xmx = max(xmx, x0 + 2); ymn = min(ymn, y); ymx = max(ymx, y); }
      if (z.w > 0.0f) { xmn = min(xmn, x0 + 3); xmx = max(xmx, x0 + 3); ymn = min(ymn, y); ymx = max(ymx, y); }
    }
    r0[t] = xmn; r1[t] = xmx; r2[t] = ymn; r3[t] = ymx;
    __syncthreads();
    for (int s2 = 128; s2 > 0; s2 >>= 1) {
      if (t < s2) {
        r0[t] = min(r0[t], r0[t + s2]);
        r1[t] = max(r1[t], r1[t + s2]);
        r2[t] = min(r2[t], r2[t + s2]);
        r3[t] = max(r3[t], r3[t + s2]);
      }
      __syncthreads();
    }
    if (t == 0) {
      int* o = bbp + ((size_t)b * kBXB + c) * 4;
      o[0] = r0[0]; o[1] = r1[0]; o[2] = r2[0]; o[3] = r3[0];
    }
    return;
  }

  // rand-point CE partials
  {
    __shared__ float red[4][256];
    int i = blk - kSampleBlocks - kBboxBlocks;
    int x = i & 7;
    int s = i >> 3;                   // 0..7
    int b = x * 2 + (s & 1);
    int c = s >> 1;                   // 0..3
    const float* pred_b = pred + (size_t)b * kHW;
    const float* gt_b = gt + (size_t)b * kHW;
    float ce_s = 0.0f, p_s = 0.0f, t_s = 0.0f, pt_s = 0.0f;
    for (int e = c * 256 + t; e < kNRAND; e += kRPB * 256) {
      float2 cc = *(const float2*)&coords_rand[((size_t)b * kNRAND + e) * 2];
      float z = sample_bilinear(pred_b, cc.x, cc.y);
      float tt = sample_bilinear(gt_b, cc.x, cc.y);
      float ce, p;
      ce_pair(z, tt, ce, p);
      ce_s += ce; p_s += p; t_s += tt; pt_s += p * tt;
    }
    red[0][t] = ce_s; red[1][t] = p_s; red[2][t] = t_s; red[3][t] = pt_s;
    __syncthreads();
    for (int s2 = 128; s2 > 0; s2 >>= 1) {
      if (t < s2) {
        red[0][t] += red[0][t + s2];
        red[1][t] += red[1][t + s2];
        red[2][t] += red[2][t + s2];
        red[3][t] += red[3][t + s2];
      }
      __syncthreads();
    }
    if (t == 0) {
      float* o = plp + ((size_t)b * kRPB + c) * 4;
      o[0] = red[0][0]; o[1] = red[1][0]; o[2] = red[2][0]; o[3] = red[3][0];
    }
  }
}

// ---- K2: select+CE-sum (blocks 0..15) | region (blocks 16..271) ----
__global__ __launch_bounds__(1024) void fused2_kernel(const unsigned* __restrict__ pu,
                                                      const float4* __restrict__ trm,
                                                      const float* __restrict__ pred,
                                                      const float* __restrict__ gt,
                                                      const int* __restrict__ bbp,
                                                      float* __restrict__ osp,
                                                      float* __restrict__ rgp) {
  __shared__ unsigned smem[16 * kHStride + 1024];   // hist | sums/cand (69.7 KB)
  __shared__ int s_bstar, s_need, s_ccnt, s_round;
  int blk = blockIdx.x;
  int t = threadIdx.x;

  if (blk < kB) {
    constexpr int C4 = 10;           // ceil(9408/1024) uint4 groups per thread
    constexpr int CAP = 1024;
    int b = (blk & 7) * 2 + (blk >> 3);   // batch b on XCD b/2 (matches K1 residue)
    const uint4* pu4_b = (const uint4*)(pu + (size_t)b * kNS);
    const float4* trm_b = trm + (size_t)b * kNS;
    unsigned* hist = smem;
    unsigned* sums = smem + 16 * kHStride;

    for (int i = t; i < 16 * kHStride; i += 1024) hist[i] = 0u;
    if (t == 0) s_ccnt = 0;
    __syncthreads();

    // pass 1: issue ALL uint4 loads first (10 in flight), then histogram
    uint4 ub4[C4];
#pragma unroll
    for (int j = 0; j < C4; ++j) {
      int idx4 = j * 1024 + t;
      if (idx4 < kNS4) {
        ub4[j] = pu4_b[idx4];
      } else {
        ub4[j] = make_uint4(0xffffffffu, 0xffffffffu, 0xffffffffu, 0xffffffffu);
      }
    }
#pragma unroll
    for (int j = 0; j < C4; ++j) {
      if (j * 1024 + t < kNS4) {
        atomicAdd(&hist[SW((int)(ub4[j].x >> 17))], 1u);
        atomicAdd(&hist[SW((int)(ub4[j].y >> 17))], 1u);
        atomicAdd(&hist[SW((int)(ub4[j].z >> 17))], 1u);
        atomicAdd(&hist[SW((int)(ub4[j].w >> 17))], 1u);
      }
    }
    __syncthreads();

    // boundary search (verified in r7): 16-bin sums -> 64-supergroup shfl scans
    unsigned s = 0;
#pragma unroll
    for (int k = 0; k < 16; ++k) s += hist[k * kHStride + t];  // bins t*16..t*16+15
    sums[t] = s;
    __syncthreads();
    if (t < 64) {
      const unsigned K = (unsigned)kNUNC;
      unsigned v = 0;
#pragma unroll
      for (int k = 0; k < 16; ++k) v += sums[t * 16 + k];      // bins t*256..
      unsigned cum = v;
      for (int off = 1; off < 64; off <<= 1) {
        unsigned xx = __shfl_up(cum, off, 64);
        if (t >= off) cum += xx;
      }
      unsigned long long m = __ballot(cum >= K);
      int L = (int)__ffsll(m) - 1;
      unsigned base1 = __shfl(cum - v, L, 64);
      unsigned v2 = (t < 16) ? sums[L * 16 + t] : 0u;
      unsigned cum2 = v2;
      for (int off = 1; off < 16; off <<= 1) {
        unsigned xx = __shfl_up(cum2, off, 64);
        if (t >= off) cum2 += xx;
      }
      unsigned long long m2 = __ballot((t < 16) && (base1 + cum2 >= K));
      int M = (int)__ffsll(m2) - 1;
      unsigned base2 = __shfl(base1 + cum2 - v2, M, 64);
      int E = L * 16 + M;
      unsigned v3 = (t < 16) ? hist[t * kHStride + E] : 0u;
      unsigned cum3 = v3;
      for (int off = 1; off < 16; off <<= 1) {
        unsigned xx = __shfl_up(cum3, off, 64);
        if (t >= off) cum3 += xx;
      }
      unsigned long long m3 = __ballot((t < 16) && (base2 + cum3 >= K));
      int F = (int)__ffsll(m3) - 1;
      if (t == F) {
        s_bstar = E * 16 + F;
        s_need = (int)(K - (base2 + cum3 - v3));
      }
    }
    __syncthreads();
    int bstar = s_bstar;
    int need = s_need;

    // compress membership to register bitmasks; ub4 dies here (low VGPR stream)
    unsigned long long lt = 0ull, eq = 0ull;
#pragma unroll
    for (int j = 0; j < C4; ++j) {
      int b0 = (int)(ub4[j].x >> 17), b1 = (int)(ub4[j].y >> 17);
      int b2 = (int)(ub4[j].z >> 17), b3 = (int)(ub4[j].w >> 17);
      unsigned mlt = (unsigned)(b0 < bstar) | ((unsigned)(b1 < bstar) << 1) |
                     ((unsigned)(b2 < bstar) << 2) | ((unsigned)(b3 < bstar) << 3);
      unsigned meq = (unsigned)(b0 == bstar) | ((unsigned)(b1 == bstar) << 1) |
                     ((unsigned)(b2 == bstar) << 2) | ((unsigned)(b3 == bstar) << 3);
      lt |= (unsigned long long)mlt << (j * 4);
      eq |= (unsigned long long)meq << (j * 4);
    }

    // pass 2: unconditional float4 streaming + branchless masked accumulate
    int* cand = (int*)sums;
    float ce_s = 0.0f, p_s = 0.0f, t_s = 0.0f, pt_s = 0.0f;
#pragma unroll 2
    for (int j = 0; j < C4; ++j) {
      int idx4 = j * 1024 + t;
      if (idx4 < kNS4) {
        const float4* base = trm_b + (size_t)idx4 * 4;
        float4 q0 = base[0];
        float4 q1 = base[1];
        float4 q2 = base[2];
        float4 q3 = base[3];
        unsigned mlt = (unsigned)((lt >> (j * 4)) & 0xFull);
        float w0 = (mlt & 1u) ? 1.0f : 0.0f;
        float w1 = (mlt & 2u) ? 1.0f : 0.0f;
        float w2 = (mlt & 4u) ? 1.0f : 0.0f;
        float w3 = (mlt & 8u) ? 1.0f : 0.0f;
        ce_s += w0 * q0.x + w1 * q1.x + w2 * q2.x + w3 * q3.x;
        p_s  += w0 * q0.y + w1 * q1.y + w2 * q2.y + w3 * q3.y;
        t_s  += w0 * q0.z + w1 * q1.z + w2 * q2.z + w3 * q3.z;
        pt_s += w0 * q0.w + w1 * q1.w + w2 * q2.w + w3 * q3.w;
        unsigned meq = (unsigned)((eq >> (j * 4)) & 0xFull);
        while (meq) {
          int e = __ffs(meq) - 1;
          meq &= meq - 1;
          int pos = atomicAdd(&s_ccnt, 1);
          if (pos < CAP) cand[pos] = idx4 * 4 + e;
        }
      }
    }
    __syncthreads();
    int c = s_ccnt;

    if (c <= CAP) {
      for (int i = t; i < c; i += 1024) {
        int my = cand[i];
        int r = 0;
        for (int k = 0; k < c; ++k) r += (cand[k] < my) ? 1 : 0;
        if (r < need) {
          float4 q = trm_b[my];
          ce_s += q.x; p_s += q.y; t_s += q.z; pt_s += q.w;
        }
      }
      __syncthreads();
    } else {
      // ordered-scan fallback over eq bits (pathological duplicate-heavy data)
      if (t == 0) s_round = 0;
      __syncthreads();
      for (int j = 0; j < C4; ++j) {
        int idx4 = j * 1024 + t;
        unsigned meq = (idx4 < kNS4) ? (unsigned)((eq >> (j * 4)) & 0xFull) : 0u;
        unsigned cnt = __popc(meq);
        sums[t] = cnt;
        __syncthreads();
        for (int off = 1; off < 1024; off <<= 1) {
          unsigned v = (t >= off) ? sums[t - off] : 0u;
          __syncthreads();
          sums[t] += v;
          __syncthreads();
        }
        int myBase = s_round + (int)(sums[t] - cnt);
        unsigned mm = meq;
        while (mm) {
          int e = __ffs(mm) - 1;
          mm &= mm - 1;
          if (myBase < need) {
            float4 q = trm_b[idx4 * 4 + e];
            ce_s += q.x; p_s += q.y; t_s += q.z; pt_s += q.w;
          }
          myBase++;
        }
        __syncthreads();
        if (t == 0) s_round += (int)sums[1023];
        __syncthreads();
      }
    }

    // reduce 4 sums: per-wave shfl -> 16 wave partials -> thread 0
    float* redf = (float*)smem;
    float vals[4] = {ce_s, p_s, t_s, pt_s};
#pragma unroll
    for (int q = 0; q < 4; ++q) {
      float v = vals[q];
      for (int o = 32; o > 0; o >>= 1) v += __shfl_down(v, o, 64);
      if ((t & 63) == 0) redf[(t >> 6) * 4 + q] = v;
    }
    __syncthreads();
    if (t == 0) {
      float o0 = 0, o1 = 0, o2 = 0, o3 = 0;
      for (int w = 0; w < 16; ++w) {
        o0 += redf[w * 4 + 0]; o1 += redf[w * 4 + 1];
        o2 += redf[w * 4 + 2]; o3 += redf[w * 4 + 3];
      }
      float* o = osp + (size_t)b * 4;
      o[0] = o0; o[1] = o1; o[2] = o2; o[3] = o3;
    }
    return;
  }

  // region portion (1024 threads/block), XCD-clustered: batch b on XCD b/2
  {
    constexpr int CHUNK4 = kHW / kRGB2 / 4;  // 4096 float4 per block
    int i = blk - kB;
    int x = i & 7;
    int s = i >> 3;                   // 0..31
    int b = x * 2 + (s & 1);
    int c = s >> 1;                   // 0..15
    const float4* pred4 = (const float4*)(pred + (size_t)b * kHW) + (size_t)c * CHUNK4;
    const float4* gt4 = (const float4*)(gt + (size_t)b * kHW) + (size_t)c * CHUNK4;

    int xmn = kW, xmx = -1, ymn = kH, ymx = -1;
#pragma unroll
    for (int u = 0; u < kBXB; ++u) {
      const int4 pb = *(const int4*)(bbp + ((size_t)b * kBXB + u) * 4);
      xmn = min(xmn, pb.x); xmx = max(xmx, pb.y);
      ymn = min(ymn, pb.z); ymx = max(ymx, pb.w);
    }
    bool empty = (xmx < 0);
    int x1 = empty ? 0 : xmn;
    int x2 = min(empty ? (kW - 1) : xmx, kW - 1);
    int y1 = empty ? 0 : ymn;
    int y2 = min(empty ? (kH - 1) : ymx, kH - 1);
    bool valid = (x2 > x1) && (y2 > y1);

    int pbase = c * CHUNK4 * 4;
    float wsum = 0.0f, bcew = 0.0f, inter = 0.0f, pw = 0.0f, gw = 0.0f;
    for (int i4 = t; i4 < CHUNK4; i4 += 1024) {
      float4 zv = pred4[i4];
      float4 gv = gt4[i4];
      int p = pbase + i4 * 4;
      int y = p >> 9;
      int x0 = p & (kW - 1);
      bool iny = valid && (y >= y1) && (y <= y2);
#pragma unroll
      for (int l = 0; l < 4; ++l) {
        float z = (l == 0) ? zv.x : (l == 1) ? zv.y : (l == 2) ? zv.z : zv.w;
        float g = (l == 0) ? gv.x : (l == 1) ? gv.y : (l == 2) ? gv.z : gv.w;
        int xx = x0 + l;
        float w = (iny && xx >= x1 && xx <= x2) ? 2.0f : 0.5f;
        float a = expf(-fabsf(z));
        float sp = fmaxf(-z, 0.0f) + log1pf(a);   // softplus(-z) = -log_sigmoid(z)
        float bce = sp + (1.0f - g) * z;
        float inv = 1.0f / (1.0f + a);
        float pp = (z >= 0.0f) ? inv : a * inv;
        wsum += w;
        bcew += bce * w;
        inter += pp * g * w;
        pw += pp * w;
        gw += g * w;
      }
    }
    float* redf = (float*)smem;
    float vals[5] = {wsum, bcew, inter, pw, gw};
#pragma unroll
    for (int q5 = 0; q5 < 5; ++q5) {
      float v = vals[q5];
      for (int o = 32; o > 0; o >>= 1) v += __shfl_down(v, o, 64);
      if ((t & 63) == 0) redf[(t >> 6) * 5 + q5] = v;
    }
    __syncthreads();
    if (t == 0) {
      float o0 = 0, o1 = 0, o2 = 0, o3 = 0, o4 = 0;
      for (int w = 0; w < 16; ++w) {
        o0 += redf[w * 5 + 0]; o1 += redf[w * 5 + 1]; o2 += redf[w * 5 + 2];
        o3 += redf[w * 5 + 3]; o4 += redf[w * 5 + 4];
      }
      float* o = rgp + ((size_t)b * kRGB2 + c) * 5;
      o[0] = o0; o[1] = o1; o[2] = o2; o[3] = o3; o[4] = o4;
    }
  }
}

// ---- K3: finalize in f64 ----
__global__ __launch_bounds__(64) void finalize_kernel(const float* __restrict__ plp,
                                                      const float* __restrict__ osp,
                                                      const float* __restrict__ rgp,
                                                      float* __restrict__ out) {
  __shared__ double sh[kB][4];
  int t = threadIdx.x;
  if (t < kB) {
    const float* o = osp + (size_t)t * 4;
    double ce = o[0], p = o[1], tt = o[2], pt = o[3];
    for (int c = 0; c < kRPB; ++c) {
      const float* q = plp + ((size_t)t * kRPB + c) * 4;
      ce += q[0]; p += q[1]; tt += q[2]; pt += q[3];
    }
    double ws = 0, bc = 0, in = 0, pw = 0, gw = 0;
    for (int c = 0; c < kRGB2; ++c) {
      const float* q = rgp + ((size_t)t * kRGB2 + c) * 5;
      ws += q[0]; bc += q[1]; in += q[2]; pw += q[3]; gw += q[4];
    }
    sh[t][0] = ce / (double)kNPTS;
    sh[t][1] = 1.0 - (2.0 * pt + 1.0) / (p + tt + 1.0);
    double wss = ws > 1e-6 ? ws : 1e-6;
    sh[t][2] = bc / wss;
    sh[t][3] = 1.0 - (2.0 * in + 1.0) / (pw + gw + 1.0);
  }
  __syncthreads();
  if (t == 0) {
    double a = 0, b = 0, c = 0, d = 0;
    for (int i = 0; i < kB; ++i) { a += sh[i][0]; b += sh[i][1]; c += sh[i][2]; d += sh[i][3]; }
    out[0] = (float)(a / 16.0);
    out[1] = (float)(b / 16.0);
    out[2] = (float)(c / 16.0);
    out[3] = (float)(d / 16.0);
  }
}

extern "C" void kernel_launch(void* const* d_in, const int* in_sizes, int n_in,
                              void* d_out, int out_size, void* d_ws, size_t ws_size,
                              hipStream_t stream) {
  const float* pred = (const float*)d_in[0];
  const float* gt = (const float*)d_in[1];
  const float* coords_os = (const float*)d_in[2];
  const float* coords_rand = (const float*)d_in[3];
  float* out = (float*)d_out;
  char* ws = (char*)d_ws;

  unsigned* pu = (unsigned*)(ws + OFF_PU);
  float4* trm = (float4*)(ws + OFF_TRM);
  int* bbp = (int*)(ws + OFF_BBP);
  float* plp = (float*)(ws + OFF_PLP);
  float* osp = (float*)(ws + OFF_OSP);
  float* rgp = (float*)(ws + OFF_RGP);

  fused1_kernel<<<kSampleBlocks + kBboxBlocks + kRandBlocks, 256, 0, stream>>>(
      pred, gt, coords_os, coords_rand, pu, trm, bbp, plp);
  fused2_kernel<<<kB + kB * kRGB2, 1024, 0, stream>>>(pu, trm, pred, gt, bbp, osp, rgp);
  finalize_kernel<<<1, 64, 0, stream>>>(plp, osp, rgp, out);
}

// Round 9
// 64.937 us; speedup vs baseline: 1.3382x; 1.1490x over previous
//
#include <hip/hip_runtime.h>
#include <cstdint>
#include <cstddef>

namespace {

constexpr int kB = 16;
constexpr int kH = 512;
constexpr int kW = 512;
constexpr int kHW = kH * kW;
constexpr int kNS = 37632;     // NUM_POINTS * OVERSAMPLE
constexpr int kNS4 = kNS / 4;  // 9408 uint4/float4 groups per batch
constexpr int kNUNC = 9408;    // 0.75 * NUM_POINTS
constexpr int kNRAND = 3136;
constexpr int kNPTS = 12544;
constexpr int kBXB = 16;       // bbox partial blocks per batch
constexpr int kRPB = 4;        // rand-point blocks per batch
constexpr int kRGB2 = 16;      // region blocks per batch (1024 threads each)
constexpr int kPairs = kNS / 2;                  // 18816 pairs per batch
constexpr int kSampSlots = 148;                  // slots per XCD (2 batches x 74 chunks)
constexpr int kSampleBlocks = 8 * kSampSlots;    // 1184
constexpr int kBboxBlocks = kB * kBXB;           // 256
constexpr int kRandBlocks = kB * kRPB;           // 64
constexpr int kHStride = 1025;                   // hist row stride (words)

// workspace layout (bytes)
constexpr size_t OFF_PU  = 0;                                     // [B][NS] u32  |z| bits
constexpr size_t OFF_TRM = OFF_PU + (size_t)kB * kNS * 4;         // [B][NS] float4 (ce,p,t,pt)
constexpr size_t OFF_BBP = OFF_TRM + (size_t)kB * kNS * 16;       // [B][16][4] i32
constexpr size_t OFF_PLP = OFF_BBP + (size_t)kB * kBXB * 4 * 4;   // [B][4][4] f32 rand partials
constexpr size_t OFF_OSP = OFF_PLP + (size_t)kB * kRPB * 4 * 4;   // [B][4] f32 os sums
constexpr size_t OFF_RGP = OFF_OSP + (size_t)kB * 4 * 4;          // [B][16][5] f32 region partials

// Swizzled hist: bin -> (bin&15)*1025 + (bin>>4). Row sums hist[k*1025+t] are
// lane-stride-1 (conflict-free); 1025%32==1 keeps adjacent bins in distinct banks.
__device__ __forceinline__ int SW(int bin) {
  return (bin & 15) * kHStride + (bin >> 4);
}

} // namespace

__device__ __forceinline__ float sample_bilinear(const float* __restrict__ img,
                                                 float cx, float cy) {
  float x = cx * (float)kW - 0.5f;
  float y = cy * (float)kH - 0.5f;
  float x0f = floorf(x), y0f = floorf(y);
  float wx1 = x - x0f, wx0 = 1.0f - wx1;
  float wy1 = y - y0f, wy0 = 1.0f - wy1;
  int x0 = (int)x0f, y0 = (int)y0f;
  int x1 = x0 + 1, y1 = y0 + 1;
  int xc0 = min(max(x0, 0), kW - 1), xc1 = min(max(x1, 0), kW - 1);
  int yc0 = min(max(y0, 0), kH - 1), yc1 = min(max(y1, 0), kH - 1);
  float v00 = ((x0 >= 0) && (x0 < kW) && (y0 >= 0) && (y0 < kH)) ? img[yc0 * kW + xc0] : 0.0f;
  float v01 = ((x1 >= 0) && (x1 < kW) && (y0 >= 0) && (y0 < kH)) ? img[yc0 * kW + xc1] : 0.0f;
  float v10 = ((x0 >= 0) && (x0 < kW) && (y1 >= 0) && (y1 < kH)) ? img[yc1 * kW + xc0] : 0.0f;
  float v11 = ((x1 >= 0) && (x1 < kW) && (y1 >= 0) && (y1 < kH)) ? img[yc1 * kW + xc1] : 0.0f;
  return v00 * (wy0 * wx0) + v01 * (wy0 * wx1) + v10 * (wy1 * wx0) + v11 * (wy1 * wx1);
}

__device__ __forceinline__ void ce_pair(float z, float tt, float& ce, float& p) {
  float a = expf(-fabsf(z));
  ce = fmaxf(z, 0.0f) - z * tt + log1pf(a);
  float inv = 1.0f / (1.0f + a);
  p = (z >= 0.0f) ? inv : a * inv;
}

// ---- K1: os sampling+CE | bbox partials | rand CE partials; XCD-clustered ----
__global__ __launch_bounds__(256) void fused1_kernel(const float* __restrict__ pred,
                                                     const float* __restrict__ gt,
                                                     const float* __restrict__ coords_os,
                                                     const float* __restrict__ coords_rand,
                                                     unsigned* __restrict__ pu,
                                                     float4* __restrict__ trm,
                                                     int* __restrict__ bbp,
                                                     float* __restrict__ plp) {
  int blk = blockIdx.x;
  int t = threadIdx.x;

  if (blk < kSampleBlocks) {
    int x = blk & 7;
    int s = blk >> 3;                 // 0..147
    int b = x * 2 + (s & 1);
    int chunk = s >> 1;               // 0..73
    int pib = chunk * 256 + t;        // pair index within batch
    if (pib >= kPairs) return;
    size_t gp = (size_t)b * kPairs + pib;   // global pair index
    float4 c2 = ((const float4*)coords_os)[gp];
    size_t i0 = gp * 2;
    const float* pred_b = pred + (size_t)b * kHW;
    const float* gt_b = gt + (size_t)b * kHW;
    float z0 = sample_bilinear(pred_b, c2.x, c2.y);
    float z1 = sample_bilinear(pred_b, c2.z, c2.w);
    float t0 = sample_bilinear(gt_b, c2.x, c2.y);
    float t1 = sample_bilinear(gt_b, c2.z, c2.w);
    float ce0, p0, ce1, p1;
    ce_pair(z0, t0, ce0, p0);
    ce_pair(z1, t1, ce1, p1);
    unsigned u0 = __float_as_uint(z0) & 0x7fffffffu;
    unsigned u1 = __float_as_uint(z1) & 0x7fffffffu;
    *(uint2*)&pu[i0] = make_uint2(u0, u1);
    trm[i0] = make_float4(ce0, p0, t0, p0 * t0);
    trm[i0 + 1] = make_float4(ce1, p1, t1, p1 * t1);
    return;
  }

  if (blk < kSampleBlocks + kBboxBlocks) {
    __shared__ int r0[256], r1[256], r2[256], r3[256];
    int i = blk - kSampleBlocks;
    int x = i & 7;
    int s = i >> 3;                   // 0..31
    int b = x * 2 + (s & 1);
    int c = s >> 1;                   // 0..15
    constexpr int CHUNK4 = kHW / kBXB / 4;  // 4096 float4
    const float4* pred4 = (const float4*)(pred + (size_t)b * kHW) + (size_t)c * CHUNK4;
    int pbase = c * CHUNK4 * 4;
    int xmn = kW, xmx = -1, ymn = kH, ymx = -1;
    for (int i4 = t; i4 < CHUNK4; i4 += 256) {
      float4 z = pred4[i4];
      int p = pbase + i4 * 4;
      int y = p >> 9;
      int x0 = p & (kW - 1);
      if (z.x > 0.0f) { xmn = min(xmn, x0);     xmx = max(xmx, x0);     ymn = min(ymn, y); ymx = max(ymx, y); }
      if (z.y > 0.0f) { xmn = min(xmn, x0 + 1); xmx = max(xmx, x0 + 1); ymn = min(ymn, y); ymx = max(ymx, y); }
      if (z.z > 0.0f) { xmn = min(xmn, x0 + 2); xmx = max(xmx, x0 + 2); ymn = min(ymn, y); ymx = max(ymx, y); }
      if (z.w > 0.0f) { xmn = min(xmn, x0 + 3); xmx = max(xmx, x0 + 3); ymn = min(ymn, y); ymx = max(ymx, y); }
    }
    r0[t] = xmn; r1[t] = xmx; r2[t] = ymn; r3[t] = ymx;
    __syncthreads();
    for (int s2 = 128; s2 > 0; s2 >>= 1) {
      if (t < s2) {
        r0[t] = min(r0[t], r0[t + s2]);
        r1[t] = max(r1[t], r1[t + s2]);
        r2[t] = min(r2[t], r2[t + s2]);
        r3[t] = max(r3[t], r3[t + s2]);
      }
      __syncthreads();
    }
    if (t == 0) {
      int* o = bbp + ((size_t)b * kBXB + c) * 4;
      o[0] = r0[0]; o[1] = r1[0]; o[2] = r2[0]; o[3] = r3[0];
    }
    return;
  }

  // rand-point CE partials
  {
    __shared__ float red[4][256];
    int i = blk - kSampleBlocks - kBboxBlocks;
    int x = i & 7;
    int s = i >> 3;                   // 0..7
    int b = x * 2 + (s & 1);
    int c = s >> 1;                   // 0..3
    const float* pred_b = pred + (size_t)b * kHW;
    const float* gt_b = gt + (size_t)b * kHW;
    float ce_s = 0.0f, p_s = 0.0f, t_s = 0.0f, pt_s = 0.0f;
    for (int e = c * 256 + t; e < kNRAND; e += kRPB * 256) {
      float2 cc = *(const float2*)&coords_rand[((size_t)b * kNRAND + e) * 2];
      float z = sample_bilinear(pred_b, cc.x, cc.y);
      float tt = sample_bilinear(gt_b, cc.x, cc.y);
      float ce, p;
      ce_pair(z, tt, ce, p);
      ce_s += ce; p_s += p; t_s += tt; pt_s += p * tt;
    }
    red[0][t] = ce_s; red[1][t] = p_s; red[2][t] = t_s; red[3][t] = pt_s;
    __syncthreads();
    for (int s2 = 128; s2 > 0; s2 >>= 1) {
      if (t < s2) {
        red[0][t] += red[0][t + s2];
        red[1][t] += red[1][t + s2];
        red[2][t] += red[2][t + s2];
        red[3][t] += red[3][t + s2];
      }
      __syncthreads();
    }
    if (t == 0) {
      float* o = plp + ((size_t)b * kRPB + c) * 4;
      o[0] = red[0][0]; o[1] = red[1][0]; o[2] = red[2][0]; o[3] = red[3][0];
    }
  }
}

// ---- K2: select+CE-sum (blocks 0..15) | region (blocks 16..271) ----
// Select path holds NO per-thread arrays across phases (re-reads pu, L2-hot)
// to avoid scratch spill at the 64-VGPR/8-wave budget.
__global__ __launch_bounds__(1024) void fused2_kernel(const unsigned* __restrict__ pu,
                                                      const float4* __restrict__ trm,
                                                      const float* __restrict__ pred,
                                                      const float* __restrict__ gt,
                                                      const int* __restrict__ bbp,
                                                      float* __restrict__ osp,
                                                      float* __restrict__ rgp) {
  __shared__ unsigned smem[16 * kHStride + 1024];   // hist | sums/cand (69.7 KB)
  __shared__ int s_bstar, s_need, s_ccnt, s_round;
  int blk = blockIdx.x;
  int t = threadIdx.x;

  if (blk < kB) {
    constexpr int C4 = 10;           // ceil(9408/1024) uint4 groups per thread
    constexpr int CAP = 1024;
    int b = (blk & 7) * 2 + (blk >> 3);   // batch b on XCD b/2 (matches K1 residue)
    const uint4* pu4_b = (const uint4*)(pu + (size_t)b * kNS);
    const float4* trm_b = trm + (size_t)b * kNS;
    unsigned* hist = smem;
    unsigned* sums = smem + 16 * kHStride;

    for (int i = t; i < 16 * kHStride; i += 1024) hist[i] = 0u;
    if (t == 0) s_ccnt = 0;
    __syncthreads();

    // pass 1: load -> histogram -> drop (no live array)
#pragma unroll 2
    for (int j = 0; j < C4; ++j) {
      int idx4 = j * 1024 + t;
      if (idx4 < kNS4) {
        uint4 u = pu4_b[idx4];
        atomicAdd(&hist[SW((int)(u.x >> 17))], 1u);
        atomicAdd(&hist[SW((int)(u.y >> 17))], 1u);
        atomicAdd(&hist[SW((int)(u.z >> 17))], 1u);
        atomicAdd(&hist[SW((int)(u.w >> 17))], 1u);
      }
    }
    __syncthreads();

    // boundary search: 16-bin sums -> 64-supergroup shfl scans (verified r7)
    unsigned s = 0;
#pragma unroll
    for (int k = 0; k < 16; ++k) s += hist[k * kHStride + t];  // bins t*16..t*16+15
    sums[t] = s;
    __syncthreads();
    if (t < 64) {
      const unsigned K = (unsigned)kNUNC;
      unsigned v = 0;
#pragma unroll
      for (int k = 0; k < 16; ++k) v += sums[t * 16 + k];      // bins t*256..
      unsigned cum = v;
      for (int off = 1; off < 64; off <<= 1) {
        unsigned xx = __shfl_up(cum, off, 64);
        if (t >= off) cum += xx;
      }
      unsigned long long m = __ballot(cum >= K);
      int L = (int)__ffsll(m) - 1;
      unsigned base1 = __shfl(cum - v, L, 64);
      unsigned v2 = (t < 16) ? sums[L * 16 + t] : 0u;
      unsigned cum2 = v2;
      for (int off = 1; off < 16; off <<= 1) {
        unsigned xx = __shfl_up(cum2, off, 64);
        if (t >= off) cum2 += xx;
      }
      unsigned long long m2 = __ballot((t < 16) && (base1 + cum2 >= K));
      int M = (int)__ffsll(m2) - 1;
      unsigned base2 = __shfl(base1 + cum2 - v2, M, 64);
      int E = L * 16 + M;
      unsigned v3 = (t < 16) ? hist[t * kHStride + E] : 0u;
      unsigned cum3 = v3;
      for (int off = 1; off < 16; off <<= 1) {
        unsigned xx = __shfl_up(cum3, off, 64);
        if (t >= off) cum3 += xx;
      }
      unsigned long long m3 = __ballot((t < 16) && (base2 + cum3 >= K));
      int F = (int)__ffsll(m3) - 1;
      if (t == F) {
        s_bstar = E * 16 + F;
        s_need = (int)(K - (base2 + cum3 - v3));
      }
    }
    __syncthreads();
    int bstar = s_bstar;
    int need = s_need;

    // pass 2: re-load pu (L2-hot) + unconditional float4 stream, branchless
    int* cand = (int*)sums;
    float ce_s = 0.0f, p_s = 0.0f, t_s = 0.0f, pt_s = 0.0f;
#pragma unroll 2
    for (int j = 0; j < C4; ++j) {
      int idx4 = j * 1024 + t;
      if (idx4 < kNS4) {
        uint4 u = pu4_b[idx4];
        const float4* base = trm_b + (size_t)idx4 * 4;
        float4 q0 = base[0];
        float4 q1 = base[1];
        float4 q2 = base[2];
        float4 q3 = base[3];
        int b0 = (int)(u.x >> 17), b1 = (int)(u.y >> 17);
        int b2 = (int)(u.z >> 17), b3 = (int)(u.w >> 17);
        float w0 = (b0 < bstar) ? 1.0f : 0.0f;
        float w1 = (b1 < bstar) ? 1.0f : 0.0f;
        float w2 = (b2 < bstar) ? 1.0f : 0.0f;
        float w3 = (b3 < bstar) ? 1.0f : 0.0f;
        ce_s += w0 * q0.x + w1 * q1.x + w2 * q2.x + w3 * q3.x;
        p_s  += w0 * q0.y + w1 * q1.y + w2 * q2.y + w3 * q3.y;
        t_s  += w0 * q0.z + w1 * q1.z + w2 * q2.z + w3 * q3.z;
        pt_s += w0 * q0.w + w1 * q1.w + w2 * q2.w + w3 * q3.w;
        if (b0 == bstar) { int pos = atomicAdd(&s_ccnt, 1); if (pos < CAP) cand[pos] = idx4 * 4 + 0; }
        if (b1 == bstar) { int pos = atomicAdd(&s_ccnt, 1); if (pos < CAP) cand[pos] = idx4 * 4 + 1; }
        if (b2 == bstar) { int pos = atomicAdd(&s_ccnt, 1); if (pos < CAP) cand[pos] = idx4 * 4 + 2; }
        if (b3 == bstar) { int pos = atomicAdd(&s_ccnt, 1); if (pos < CAP) cand[pos] = idx4 * 4 + 3; }
      }
    }
    __syncthreads();
    int c = s_ccnt;

    if (c <= CAP) {
      for (int i = t; i < c; i += 1024) {
        int my = cand[i];
        int r = 0;
        for (int k = 0; k < c; ++k) r += (cand[k] < my) ? 1 : 0;
        if (r < need) {
          float4 q = trm_b[my];
          ce_s += q.x; p_s += q.y; t_s += q.z; pt_s += q.w;
        }
      }
      __syncthreads();
    } else {
      // ordered-scan fallback (pathological duplicate-heavy data); re-loads pu
      if (t == 0) s_round = 0;
      __syncthreads();
      for (int j = 0; j < C4; ++j) {
        int idx4 = j * 1024 + t;
        unsigned meq = 0u;
        if (idx4 < kNS4) {
          uint4 u = pu4_b[idx4];
          meq = (unsigned)((int)(u.x >> 17) == bstar) |
                ((unsigned)((int)(u.y >> 17) == bstar) << 1) |
                ((unsigned)((int)(u.z >> 17) == bstar) << 2) |
                ((unsigned)((int)(u.w >> 17) == bstar) << 3);
        }
        unsigned cnt = __popc(meq);
        sums[t] = cnt;
        __syncthreads();
        for (int off = 1; off < 1024; off <<= 1) {
          unsigned v = (t >= off) ? sums[t - off] : 0u;
          __syncthreads();
          sums[t] += v;
          __syncthreads();
        }
        int myBase = s_round + (int)(sums[t] - cnt);
        unsigned mm = meq;
        while (mm) {
          int e = __ffs(mm) - 1;
          mm &= mm - 1;
          if (myBase < need) {
            float4 q = trm_b[idx4 * 4 + e];
            ce_s += q.x; p_s += q.y; t_s += q.z; pt_s += q.w;
          }
          myBase++;
        }
        __syncthreads();
        if (t == 0) s_round += (int)sums[1023];
        __syncthreads();
      }
    }

    // reduce 4 sums: per-wave shfl -> 16 wave partials -> thread 0
    float* redf = (float*)smem;
    float vals[4] = {ce_s, p_s, t_s, pt_s};
#pragma unroll
    for (int q = 0; q < 4; ++q) {
      float v = vals[q];
      for (int o = 32; o > 0; o >>= 1) v += __shfl_down(v, o, 64);
      if ((t & 63) == 0) redf[(t >> 6) * 4 + q] = v;
    }
    __syncthreads();
    if (t == 0) {
      float o0 = 0, o1 = 0, o2 = 0, o3 = 0;
      for (int w = 0; w < 16; ++w) {
        o0 += redf[w * 4 + 0]; o1 += redf[w * 4 + 1];
        o2 += redf[w * 4 + 2]; o3 += redf[w * 4 + 3];
      }
      float* o = osp + (size_t)b * 4;
      o[0] = o0; o[1] = o1; o[2] = o2; o[3] = o3;
    }
    return;
  }

  // region portion (1024 threads/block), XCD-clustered: batch b on XCD b/2
  {
    constexpr int CHUNK4 = kHW / kRGB2 / 4;  // 4096 float4 per block
    int i = blk - kB;
    int x = i & 7;
    int s = i >> 3;                   // 0..31
    int b = x * 2 + (s & 1);
    int c = s >> 1;                   // 0..15
    const float4* pred4 = (const float4*)(pred + (size_t)b * kHW) + (size_t)c * CHUNK4;
    const float4* gt4 = (const float4*)(gt + (size_t)b * kHW) + (size_t)c * CHUNK4;

    int xmn = kW, xmx = -1, ymn = kH, ymx = -1;
#pragma unroll
    for (int u = 0; u < kBXB; ++u) {
      const int4 pb = *(const int4*)(bbp + ((size_t)b * kBXB + u) * 4);
      xmn = min(xmn, pb.x); xmx = max(xmx, pb.y);
      ymn = min(ymn, pb.z); ymx = max(ymx, pb.w);
    }
    bool empty = (xmx < 0);
    int x1 = empty ? 0 : xmn;
    int x2 = min(empty ? (kW - 1) : xmx, kW - 1);
    int y1 = empty ? 0 : ymn;
    int y2 = min(empty ? (kH - 1) : ymx, kH - 1);
    bool valid = (x2 > x1) && (y2 > y1);

    int pbase = c * CHUNK4 * 4;
    float wsum = 0.0f, bcew = 0.0f, inter = 0.0f, pw = 0.0f, gw = 0.0f;
    for (int i4 = t; i4 < CHUNK4; i4 += 1024) {
      float4 zv = pred4[i4];
      float4 gv = gt4[i4];
      int p = pbase + i4 * 4;
      int y = p >> 9;
      int x0 = p & (kW - 1);
      bool iny = valid && (y >= y1) && (y <= y2);
#pragma unroll
      for (int l = 0; l < 4; ++l) {
        float z = (l == 0) ? zv.x : (l == 1) ? zv.y : (l == 2) ? zv.z : zv.w;
        float g = (l == 0) ? gv.x : (l == 1) ? gv.y : (l == 2) ? gv.z : gv.w;
        int xx = x0 + l;
        float w = (iny && xx >= x1 && xx <= x2) ? 2.0f : 0.5f;
        float a = expf(-fabsf(z));
        float sp = fmaxf(-z, 0.0f) + log1pf(a);   // softplus(-z) = -log_sigmoid(z)
        float bce = sp + (1.0f - g) * z;
        float inv = 1.0f / (1.0f + a);
        float pp = (z >= 0.0f) ? inv : a * inv;
        wsum += w;
        bcew += bce * w;
        inter += pp * g * w;
        pw += pp * w;
        gw += g * w;
      }
    }
    float* redf = (float*)smem;
    float vals[5] = {wsum, bcew, inter, pw, gw};
#pragma unroll
    for (int q5 = 0; q5 < 5; ++q5) {
      float v = vals[q5];
      for (int o = 32; o > 0; o >>= 1) v += __shfl_down(v, o, 64);
      if ((t & 63) == 0) redf[(t >> 6) * 5 + q5] = v;
    }
    __syncthreads();
    if (t == 0) {
      float o0 = 0, o1 = 0, o2 = 0, o3 = 0, o4 = 0;
      for (int w = 0; w < 16; ++w) {
        o0 += redf[w * 5 + 0]; o1 += redf[w * 5 + 1]; o2 += redf[w * 5 + 2];
        o3 += redf[w * 5 + 3]; o4 += redf[w * 5 + 4];
      }
      float* o = rgp + ((size_t)b * kRGB2 + c) * 5;
      o[0] = o0; o[1] = o1; o[2] = o2; o[3] = o3; o[4] = o4;
    }
  }
}

// ---- K3: finalize in f64 ----
__global__ __launch_bounds__(64) void finalize_kernel(const float* __restrict__ plp,
                                                      const float* __restrict__ osp,
                                                      const float* __restrict__ rgp,
                                                      float* __restrict__ out) {
  __shared__ double sh[kB][4];
  int t = threadIdx.x;
  if (t < kB) {
    const float* o = osp + (size_t)t * 4;
    double ce = o[0], p = o[1], tt = o[2], pt = o[3];
    for (int c = 0; c < kRPB; ++c) {
      const float* q = plp + ((size_t)t * kRPB + c) * 4;
      ce += q[0]; p += q[1]; tt += q[2]; pt += q[3];
    }
    double ws = 0, bc = 0, in = 0, pw = 0, gw = 0;
    for (int c = 0; c < kRGB2; ++c) {
      const float* q = rgp + ((size_t)t * kRGB2 + c) * 5;
      ws += q[0]; bc += q[1]; in += q[2]; pw += q[3]; gw += q[4];
    }
    sh[t][0] = ce / (double)kNPTS;
    sh[t][1] = 1.0 - (2.0 * pt + 1.0) / (p + tt + 1.0);
    double wss = ws > 1e-6 ? ws : 1e-6;
    sh[t][2] = bc / wss;
    sh[t][3] = 1.0 - (2.0 * in + 1.0) / (pw + gw + 1.0);
  }
  __syncthreads();
  if (t == 0) {
    double a = 0, b = 0, c = 0, d = 0;
    for (int i = 0; i < kB; ++i) { a += sh[i][0]; b += sh[i][1]; c += sh[i][2]; d += sh[i][3]; }
    out[0] = (float)(a / 16.0);
    out[1] = (float)(b / 16.0);
    out[2] = (float)(c / 16.0);
    out[3] = (float)(d / 16.0);
  }
}

extern "C" void kernel_launch(void* const* d_in, const int* in_sizes, int n_in,
                              void* d_out, int out_size, void* d_ws, size_t ws_size,
                              hipStream_t stream) {
  const float* pred = (const float*)d_in[0];
  const float* gt = (const float*)d_in[1];
  const float* coords_os = (const float*)d_in[2];
  const float* coords_rand = (const float*)d_in[3];
  float* out = (float*)d_out;
  char* ws = (char*)d_ws;

  unsigned* pu = (unsigned*)(ws + OFF_PU);
  float4* trm = (float4*)(ws + OFF_TRM);
  int* bbp = (int*)(ws + OFF_BBP);
  float* plp = (float*)(ws + OFF_PLP);
  float* osp = (float*)(ws + OFF_OSP);
  float* rgp = (float*)(ws + OFF_RGP);

  fused1_kernel<<<kSampleBlocks + kBboxBlocks + kRandBlocks, 256, 0, stream>>>(
      pred, gt, coords_os, coords_rand, pu, trm, bbp, plp);
  fused2_kernel<<<kB + kB * kRGB2, 1024, 0, stream>>>(pu, trm, pred, gt, bbp, osp, rgp);
  finalize_kernel<<<1, 64, 0, stream>>>(plp, osp, rgp, out);
}